// Round 12
// baseline (112.364 us; speedup 1.0000x reference)
//
#include <hip/hip_runtime.h>

#define NBINS 128
#define NB2   (NBINS * NBINS)
#define TPB   1024            // 16 waves = 4 teams x 4 quadrant-waves
#define NBLK  256             // 1 block/CU
#define KC    32              // points per chunk
#define NTEAM 4
#define ROWB  128             // combined tile row: 2 dims x 32 pts x bf16

typedef __attribute__((ext_vector_type(8)))  short short8;
typedef __attribute__((ext_vector_type(16))) float f32x16;
typedef __attribute__((ext_vector_type(2)))  float f32x2;

// native 2^x (v_exp_f32); inputs finite
__device__ __forceinline__ float exp2_fast(float x) {
#if defined(__has_builtin)
#if __has_builtin(__builtin_amdgcn_exp2f)
    return __builtin_amdgcn_exp2f(x);
#else
    return exp2f(x);
#endif
#else
    return exp2f(x);
#endif
}

// packed fp32 multiply (VOP3P, CDNA): one instr for both lanes of the pair
__device__ __forceinline__ f32x2 pk_mul(f32x2 a, f32x2 b) {
    f32x2 d;
    asm("v_pk_mul_f32 %0, %1, %2" : "=v"(d) : "v"(a), "v"(b));
    return d;
}

// pack two fp32 -> two bf16 (round-half-up) in one v_perm: [bf16(b) : bf16(a)]
__device__ __forceinline__ unsigned pk_bf16(float a, float b) {
    const unsigned ar = __float_as_uint(a) + 0x8000u;
    const unsigned br = __float_as_uint(b) + 0x8000u;
    return __builtin_amdgcn_perm(br, ar, 0x07060302u);
}

// C = -0.5 * log2(e): weight(d) = exp(-0.5 d^2) = exp2(WC d^2)
#define WC (-0.72134752044448170f)
// ratio-of-ratios: w(m+1)/w(m) shrinks by 2^(2*WC) = e^-1 per step
#define E1 (0.36787944117144233f)

// LDS: double-buffered per-team COMBINED tiles, row = [dimA 64B | dimB 64B],
// XOR swizzle byte ^= (row&7)<<4 (R2 layout, counter-verified: conflicts
// 8M -> 2M vs separate tiles). 64 KB merge buffer aliases buf0 of the tiles.
union __align__(16) ShMem {
    struct {
        unsigned short tiles[2][NTEAM][NBINS][2][KC]; // [buf][team][tap][dim][pt]
        float uv[2][NTEAM][2][KC];                    // [buf][team][dim][pt]
    } s;
    float hist[NB2];
};

// Kernel 1: hist = kx^T * ky as 128x128xK bf16 MFMA GEMM (R1 pipeline,
// R2 tile layout, R8 plain-store epilogue, R9 packed recurrence).
// R12: gen regrouped to point-QUADS — 128 threads/team, 4 points each, so
// every tap write is ds_write_b64 (2x fewer LDS write ops; tile layout and
// read path unchanged). exp2 count unchanged (bands still 16-tap). Staging
// moved to team 3's upper waves (disjoint from gen waves).
__global__ __launch_bounds__(TPB, 4) void kde_mfma_kernel(
    const float* __restrict__ x,
    const float* __restrict__ ex,
    const float* __restrict__ ey,
    float* __restrict__ out,
    float* __restrict__ part,       // NBLK partial hists, or null (fallback)
    float* __restrict__ bsum,       // NBLK per-block sums (partials mode)
    int n, int nchunks)
{
    __shared__ ShMem sm;
    __shared__ float wred[TPB / 64];

    const int tid  = (int)threadIdx.x;
    const int lane = tid & 63;
    const int half = lane >> 5;          // k-half of a 16-k step
    const int l31  = lane & 31;
    const int w4   = (tid >> 6) & 3;     // wave within team
    const int team = tid >> 8;           // 0..3
    const int rowblk = (w4 >> 1) * 64;
    const int colblk = (w4 & 1) * 64;

    const float lox = ex[0], loy = ey[0];
    const float ibx = 1.0f / (ex[1] - ex[0]);
    const float iby = 1.0f / (ey[1] - ey[0]);

    // weight-gen role (team-local tt < 128): thread -> (point-QUAD, dim, band)
    const int tt   = tid & 255;
    const int pI4  = tt & 7;             // points 4*pI4 .. 4*pI4+3
    const int dimi = (tt >> 3) & 1;      // 0 = x/A half, 1 = y/B half
    const int band = (tt >> 4) & 7;      // tap band [16b, 16b+16)
    const int cI   = band * 16 + 8;      // band center row
    const float cc = (float)cI;
    const int dimbase = dimi * 64 + pI4 * 8;  // byte offset within 128B row

    // staging role: threads 896..1023 (team 3 upper waves, disjoint from gen)
    const int sid = tid - (TPB - NTEAM * KC);

    f32x16 acc[2][2];
    #pragma unroll
    for (int a = 0; a < 2; ++a)
        #pragma unroll
        for (int c = 0; c < 2; ++c)
            #pragma unroll
            for (int r = 0; r < 16; ++r) acc[a][c][r] = 0.f;

    const int niter = (nchunks + NBLK * NTEAM - 1) / (NBLK * NTEAM);

    // T14 split: ld_xy issues the global float2 load into regs;
    // write_uv drains vmcnt and writes LDS late.
    float2 xy; bool ldv = false;
    auto ld_xy = [&](int jt) {
        ldv = false;
        if (sid >= 0 && jt < niter) {
            const int tm = sid >> 5, idx = sid & 31;
            const int g  = (int)blockIdx.x * NTEAM + tm + jt * (NBLK * NTEAM);
            if (g < nchunks) {
                ldv = true;
                const int p = g * KC + idx;
                if (p < n) xy = *(const float2*)(x + (size_t)p * 6);
                else       xy = make_float2(3e9f, 3e9f);  // pad -> clamp -> 0 wt
            }
        }
    };
    auto write_uv = [&](int jt) {
        if (ldv) {
            const int tm = sid >> 5, idx = sid & 31;
            sm.s.uv[jt & 1][tm][0][idx] = (xy.x - lox) * ibx - 0.5f;
            sm.s.uv[jt & 1][tm][1][idx] = (xy.y - loy) * iby - 0.5f;
        }
    };

    // generate this thread's 16-tap band for its 4 points into tiles[jt&1].
    // Band swept outward from center c: W=exp2(WC d^2),
    // up-ratio R=exp2(WC(1-2d)), down-ratio Q=exp2(WC(1+2d)), decay E1.
    // clamp(d,+-88) keeps ratios finite for far/pad points (else 0*inf=NaN).
    // Two packed chains (points 01, 23); each tap exits as ONE ds_write_b64.
    auto gen = [&](int jt) {
        if (tt >= 128) return;
        const int g = (int)blockIdx.x * NTEAM + team + jt * (NBLK * NTEAM);
        if (g >= nchunks) return;
        const int bb = jt & 1;
        const float4 u4 = *(const float4*)&sm.s.uv[bb][team][dimi][4 * pI4];
        const float d0 = fminf(fmaxf(u4.x - cc, -88.f), 88.f);
        const float d1 = fminf(fmaxf(u4.y - cc, -88.f), 88.f);
        const float d2 = fminf(fmaxf(u4.z - cc, -88.f), 88.f);
        const float d3 = fminf(fmaxf(u4.w - cc, -88.f), 88.f);
        f32x2 W01, W23, R01, R23, Q01, Q23;
        W01.x = exp2_fast((WC * d0) * d0);  W01.y = exp2_fast((WC * d1) * d1);
        W23.x = exp2_fast((WC * d2) * d2);  W23.y = exp2_fast((WC * d3) * d3);
        R01.x = exp2_fast(fmaf(-2.f * WC, d0, WC));
        R01.y = exp2_fast(fmaf(-2.f * WC, d1, WC));
        R23.x = exp2_fast(fmaf(-2.f * WC, d2, WC));
        R23.y = exp2_fast(fmaf(-2.f * WC, d3, WC));
        Q01.x = exp2_fast(fmaf( 2.f * WC, d0, WC));
        Q01.y = exp2_fast(fmaf( 2.f * WC, d1, WC));
        Q23.x = exp2_fast(fmaf( 2.f * WC, d2, WC));
        Q23.y = exp2_fast(fmaf( 2.f * WC, d3, WC));
        const f32x2 E = { E1, E1 };
        char* tb = (char*)&sm.s.tiles[bb][team][0][0][0];
        f32x2 A01 = W01, A23 = W23;
        #pragma unroll
        for (int j = 0; j < 8; ++j) {                   // up: row = c..c+7
            const int row = cI + j;
            *(uint2*)(tb + row * ROWB + (dimbase ^ ((row & 7) << 4))) =
                make_uint2(pk_bf16(A01.x, A01.y), pk_bf16(A23.x, A23.y));
            A01 = pk_mul(A01, R01); R01 = pk_mul(R01, E);
            A23 = pk_mul(A23, R23); R23 = pk_mul(R23, E);
        }
        A01 = W01; A23 = W23;
        #pragma unroll
        for (int j = 1; j <= 8; ++j) {                  // down: row = c-1..c-8
            const int row = cI - j;
            A01 = pk_mul(A01, Q01); Q01 = pk_mul(Q01, E);
            A23 = pk_mul(A23, Q23); Q23 = pk_mul(Q23, E);
            *(uint2*)(tb + row * ROWB + (dimbase ^ ((row & 7) << 4))) =
                make_uint2(pk_bf16(A01.x, A01.y), pk_bf16(A23.x, A23.y));
        }
    };

    // MFMA for iteration it from tiles[it&1]
    auto domfma = [&](int it) {
        const int g = (int)blockIdx.x * NTEAM + team + it * (NBLK * NTEAM);
        if (g >= nchunks) return;
        const int bb = it & 1;
        const char* tb = (const char*)&sm.s.tiles[bb][team][0][0][0];
        const int ra = rowblk + l31, ca = colblk + l31;
        const int sa = (ra & 7) << 4, sb = (ca & 7) << 4; // (r+32)&7 == r&7
        #pragma unroll
        for (int s4 = 0; s4 < 2; ++s4) {
            const int kb2 = s4 * 32 + half * 16;          // k-bytes within 64B half
            const short8 a0 = *(const short8*)(tb + ra * ROWB        + ( kb2       ^ sa));
            const short8 a1 = *(const short8*)(tb + (ra + 32) * ROWB + ( kb2       ^ sa));
            const short8 b0 = *(const short8*)(tb + ca * ROWB        + ((kb2 + 64) ^ sb));
            const short8 b1 = *(const short8*)(tb + (ca + 32) * ROWB + ((kb2 + 64) ^ sb));
            acc[0][0] = __builtin_amdgcn_mfma_f32_32x32x16_bf16(a0, b0, acc[0][0], 0, 0, 0);
            acc[0][1] = __builtin_amdgcn_mfma_f32_32x32x16_bf16(a0, b1, acc[0][1], 0, 0, 0);
            acc[1][0] = __builtin_amdgcn_mfma_f32_32x32x16_bf16(a1, b0, acc[1][0], 0, 0, 0);
            acc[1][1] = __builtin_amdgcn_mfma_f32_32x32x16_bf16(a1, b1, acc[1][1], 0, 0, 0);
        }
    };

    // software pipeline: one barrier per iteration.
    // iter it: domfma reads tiles[it&1]; gen(it+1) reads uv[(it+1)&1] and
    // writes tiles[(it+1)&1]; write_uv(it+2) writes uv[it&1] — all disjoint;
    // next-iter readers separated by the barrier.
    ld_xy(0); write_uv(0);
    __syncthreads();
    ld_xy(1); gen(0); write_uv(1);
    __syncthreads();
    for (int it = 0; it < niter; ++it) {
        ld_xy(it + 2);      // issue global load (regs)
        domfma(it);         // ds_read + MFMA on current buffer
        gen(it + 1);        // trans/VALU + b64 ds_write next buffer
        write_uv(it + 2);   // vmcnt drain + 2 ds_write
        __syncthreads();
    }
    // loop ends with a barrier: safe to alias tiles with hist now.

    // merge teams into LDS hist: 4 barrier-ordered passes of plain ds ops.
    // C/D layout (verified R6): row=(r&3)+8*(r>>2)+4*half, col=l31 per tile.
    for (int tm = 0; tm < NTEAM; ++tm) {
        if (team == tm) {
            #pragma unroll
            for (int rb = 0; rb < 2; ++rb)
                #pragma unroll
                for (int tj = 0; tj < 2; ++tj)
                    #pragma unroll
                    for (int r = 0; r < 16; ++r) {
                        const int row = rowblk + rb * 32 + (r & 3) + 8 * (r >> 2) + 4 * half;
                        const int col = colblk + tj * 32 + l31;
                        const int a = row * NBINS + col;
                        const float v = acc[rb][tj][r];
                        if (tm == 0) sm.hist[a] = v;
                        else         sm.hist[a] += v;
                    }
        }
        __syncthreads();
    }

    if (part) {
        // stream the block partial out (64 KB plain coalesced float4 stores)
        // and fold the block sum in the same pass (free ALU under stores);
        // block sum exits via ONE plain store (no atomic, no memset needed).
        float4* dst = (float4*)(part + (size_t)blockIdx.x * NB2);
        const float4* src = (const float4*)sm.hist;
        float s = 0.f;
        for (int i = tid; i < NB2 / 4; i += TPB) {
            const float4 v = src[i];
            dst[i] = v;
            s += v.x + v.y + v.z + v.w;
        }
        #pragma unroll
        for (int off = 32; off > 0; off >>= 1) s += __shfl_down(s, off, 64);
        if (lane == 0) wred[tid >> 6] = s;
        __syncthreads();
        if (tid == 0) {
            float t = 0.f;
            #pragma unroll
            for (int i = 0; i < TPB / 64; ++i) t += wred[i];
            bsum[blockIdx.x] = t;
        }
    } else {
        // fallback: device-atomic merge into out (zeroed host-side)
        for (int i = tid; i < NB2; i += TPB)
            unsafeAtomicAdd(&out[i], sm.hist[i]);
    }
}

// Kernel 2 (partials mode): 256 blocks; block b reduces output elements
// [64b, 64b+64) across the 256 partials (coalesced 256B runs, LLC-resident)
// and normalizes with the global sum folded from bsum[256] (1 KB, local
// reduce — no atomics, no spin; visibility via the dispatch boundary).
__global__ __launch_bounds__(256) void kde_reduce_kernel(
    float* __restrict__ out,
    const float* __restrict__ part,
    const float* __restrict__ bsum,
    const float* __restrict__ ex,
    const float* __restrict__ ey)
{
    __shared__ float smr[4][64];
    __shared__ float sred[4];
    const int tid = (int)threadIdx.x, b = (int)blockIdx.x;
    const int g = tid >> 6, l = tid & 63;

    // global sum from the 256 per-block sums
    float s = bsum[tid];
    #pragma unroll
    for (int off = 32; off > 0; off >>= 1) s += __shfl_down(s, off, 64);
    if (l == 0) sred[g] = s;

    float v = 0.f;
    const float* base = part + b * 64 + l;
    #pragma unroll 4
    for (int p = g; p < NBLK; p += 4)
        v += base[(size_t)p * NB2];
    smr[g][l] = v;
    __syncthreads();

    if (g == 0) {
        const float tot = smr[0][l] + smr[1][l] + smr[2][l] + smr[3][l];
        const float S = sred[0] + sred[1] + sred[2] + sred[3];
        const float inv = (1.0f / (ex[1] - ex[0])) * (1.0f / (ey[1] - ey[0])) / S;
        out[b * 64 + l] = tot * inv;
    }
}

// Kernel 2 (fallback mode): single block; total-reduce, normalize in place.
__global__ __launch_bounds__(1024) void kde_final_kernel(
    float* __restrict__ out,
    const float* __restrict__ ex,
    const float* __restrict__ ey)
{
    __shared__ float red[1024 / 64];
    __shared__ float sinv;
    const int tid = (int)threadIdx.x;

    float4 v[4];
    float s = 0.f;
    #pragma unroll
    for (int i = 0; i < 4; ++i) {
        v[i] = ((const float4*)out)[tid + i * 1024];
        s += v[i].x + v[i].y + v[i].z + v[i].w;
    }
    #pragma unroll
    for (int off = 32; off > 0; off >>= 1) s += __shfl_down(s, off, 64);
    if ((tid & 63) == 0) red[tid >> 6] = s;
    __syncthreads();
    if (tid == 0) {
        float t = 0.f;
        #pragma unroll
        for (int i = 0; i < 1024 / 64; ++i) t += red[i];
        sinv = 1.0f / (t * (ex[1] - ex[0]) * (ey[1] - ey[0]));
    }
    __syncthreads();
    const float inv = sinv;
    #pragma unroll
    for (int i = 0; i < 4; ++i) {
        float4 o = v[i];
        o.x *= inv; o.y *= inv; o.z *= inv; o.w *= inv;
        ((float4*)out)[tid + i * 1024] = o;
    }
}

extern "C" void kernel_launch(void* const* d_in, const int* in_sizes, int n_in,
                              void* d_out, int out_size, void* d_ws, size_t ws_size,
                              hipStream_t stream)
{
    const float* x  = (const float*)d_in[0];
    const float* ex = (const float*)d_in[1];
    const float* ey = (const float*)d_in[2];
    float* out = (float*)d_out;
    const int n = in_sizes[0] / 6;
    const int nchunks = (n + KC - 1) / KC;

    const size_t needPart = (size_t)NBLK * NB2 * sizeof(float)
                          + (size_t)NBLK * sizeof(float);
    if (ws_size >= needPart) {
        float* part = (float*)d_ws;
        float* bsum = part + (size_t)NBLK * NB2;
        kde_mfma_kernel<<<NBLK, TPB, 0, stream>>>(x, ex, ey, out, part, bsum,
                                                  n, nchunks);
        kde_reduce_kernel<<<NBLK, 256, 0, stream>>>(out, part, bsum, ex, ey);
    } else {
        hipMemsetAsync(d_out, 0, NB2 * sizeof(float), stream);
        kde_mfma_kernel<<<NBLK, TPB, 0, stream>>>(x, ex, ey, out,
                                                  nullptr, nullptr, n, nchunks);
        kde_final_kernel<<<1, 1024, 0, stream>>>(out, ex, ey);
    }
}

// Round 13
// 101.435 us; speedup vs baseline: 1.1077x; 1.1077x over previous
//
#include <hip/hip_runtime.h>

#define NBINS 128
#define NB2   (NBINS * NBINS)
#define TPB   1024            // 16 waves = 4 teams x 4 quadrant-waves
#define NBLK  256             // 1 block/CU
#define KC    32              // points per chunk
#define NTEAM 4
#define ROWB  128             // combined tile row: 2 dims x 32 pts x bf16

typedef __attribute__((ext_vector_type(8)))  short short8;
typedef __attribute__((ext_vector_type(16))) float f32x16;
typedef __attribute__((ext_vector_type(2)))  float f32x2;

// native 2^x (v_exp_f32); inputs finite
__device__ __forceinline__ float exp2_fast(float x) {
#if defined(__has_builtin)
#if __has_builtin(__builtin_amdgcn_exp2f)
    return __builtin_amdgcn_exp2f(x);
#else
    return exp2f(x);
#endif
#else
    return exp2f(x);
#endif
}

// packed fp32 multiply (VOP3P, CDNA): one instr for both lanes of the pair
__device__ __forceinline__ f32x2 pk_mul(f32x2 a, f32x2 b) {
    f32x2 d;
    asm("v_pk_mul_f32 %0, %1, %2" : "=v"(d) : "v"(a), "v"(b));
    return d;
}

// pack two fp32 -> two bf16 (round-half-up) in one v_perm: [bf16(b) : bf16(a)]
__device__ __forceinline__ unsigned pk_bf16(float a, float b) {
    const unsigned ar = __float_as_uint(a) + 0x8000u;
    const unsigned br = __float_as_uint(b) + 0x8000u;
    return __builtin_amdgcn_perm(br, ar, 0x07060302u);
}

// C = -0.5 * log2(e): weight(d) = exp(-0.5 d^2) = exp2(WC d^2)
#define WC (-0.72134752044448170f)
// ratio-of-ratios: w(m+1)/w(m) shrinks by 2^(2*WC) = e^-1 per step
#define E1 (0.36787944117144233f)

// LDS: double-buffered per-team COMBINED tiles, row = [dimA 64B | dimB 64B],
// XOR swizzle byte ^= (row&7)<<4 (R2 layout, counter-verified: conflicts
// 8M -> 2M vs separate tiles). 64 KB merge buffer aliases buf0 of the tiles.
// R12 lesson (regression, reverted): do NOT concentrate gen on fewer threads
// for wider writes — per-wave critical path beats aggregate LDS-op count in a
// barrier-lockstep pipeline. 256 gen threads/team, b32 writes, is the floor.
union __align__(16) ShMem {
    struct {
        unsigned short tiles[2][NTEAM][NBINS][2][KC]; // [buf][team][tap][dim][pt]
        float uv[2][NTEAM][2][KC];                    // [buf][team][dim][pt]
    } s;
    float hist[NB2];
};

// Kernel 1 (measured-best configuration, R9 = 101.6 us total): hist = kx^T*ky
// as 128x128xK bf16 MFMA GEMM. R1 pipeline, R2 combined tile layout, R8
// plain-store epilogue (no 16MB atomic RMW: R3/R4 proved device atomics write
// through at ~1.45 TB/s regardless of locality), R9 packed recurrence.
// Scheduling levers measured null on this structure: T14 ld/write split (R10),
// genSetup hoist (R11); write-widening regressed (R12). This is the floor.
__global__ __launch_bounds__(TPB, 4) void kde_mfma_kernel(
    const float* __restrict__ x,
    const float* __restrict__ ex,
    const float* __restrict__ ey,
    float* __restrict__ out,
    float* __restrict__ part,       // NBLK partial hists, or null (fallback)
    float* __restrict__ bsum,       // NBLK per-block sums (partials mode)
    int n, int nchunks)
{
    __shared__ ShMem sm;
    __shared__ float wred[TPB / 64];

    const int tid  = (int)threadIdx.x;
    const int lane = tid & 63;
    const int half = lane >> 5;          // k-half of a 16-k step
    const int l31  = lane & 31;
    const int w4   = (tid >> 6) & 3;     // wave within team
    const int team = tid >> 8;           // 0..3
    const int rowblk = (w4 >> 1) * 64;
    const int colblk = (w4 & 1) * 64;

    const float lox = ex[0], loy = ey[0];
    const float ibx = 1.0f / (ex[1] - ex[0]);
    const float iby = 1.0f / (ey[1] - ey[0]);

    // weight-gen role: team-local thread -> (point-pair, dim, 16-tap band)
    const int tt     = tid & 255;
    const int pI     = tt & 15;          // point pair (points 2pI, 2pI+1)
    const int dimi   = (tt >> 4) & 1;    // 0 = x/A half, 1 = y/B half
    const int eighth = tt >> 5;          // tap band [16e, 16e+16)
    const int cI     = eighth * 16 + 8;  // band center row
    const float cc   = (float)cI;
    const int dimbase = dimi * 64 + pI * 4;  // byte offset within 128B row

    f32x16 acc[2][2];
    #pragma unroll
    for (int a = 0; a < 2; ++a)
        #pragma unroll
        for (int c = 0; c < 2; ++c)
            #pragma unroll
            for (int r = 0; r < 16; ++r) acc[a][c][r] = 0.f;

    const int niter = (nchunks + NBLK * NTEAM - 1) / (NBLK * NTEAM);

    // stage u/v for iteration jt into buffer jt&1 (threads 0..127)
    auto stage = [&](int jt) {
        if (tid < NTEAM * KC && jt < niter) {
            const int tm = tid >> 5, idx = tid & 31;
            const int g  = (int)blockIdx.x * NTEAM + tm + jt * (NBLK * NTEAM);
            if (g < nchunks) {
                const int p = g * KC + idx;
                float uu = 1e9f, vv = 1e9f;   // pad: clamp in gen -> zero weights
                if (p < n) {
                    const float2 xy = *(const float2*)(x + (size_t)p * 6);
                    uu = (xy.x - lox) * ibx - 0.5f;
                    vv = (xy.y - loy) * iby - 0.5f;
                }
                sm.s.uv[jt & 1][tm][0][idx] = uu;
                sm.s.uv[jt & 1][tm][1][idx] = vv;
            }
        }
    };

    // generate this thread's 16-tap band for iteration jt into tiles[jt&1].
    // Band swept outward from center c: w(c)=exp2(WC d^2),
    // up-ratio r=exp2(WC(1-2d)), down-ratio q=exp2(WC(1+2d)), both decay by E1.
    // clamp(d,+-88) keeps ratios finite for far/pad points (else 0*inf=NaN).
    // Recurrence runs PACKED: {a0,a1}*={r0,r1}, {r0,r1}*={E1,E1} (2 instrs).
    auto gen = [&](int jt) {
        const int g = (int)blockIdx.x * NTEAM + team + jt * (NBLK * NTEAM);
        if (g >= nchunks) return;
        const int bb = jt & 1;
        const float* uvp = sm.s.uv[bb][team][dimi];
        const float u0 = uvp[2 * pI], u1 = uvp[2 * pI + 1];
        const float d0 = fminf(fmaxf(u0 - cc, -88.f), 88.f);
        const float d1 = fminf(fmaxf(u1 - cc, -88.f), 88.f);
        const float w0 = exp2_fast((WC * d0) * d0);
        const float w1 = exp2_fast((WC * d1) * d1);
        f32x2 A, R, Q;
        A.x = w0;                               A.y = w1;
        R.x = exp2_fast(fmaf(-2.f * WC, d0, WC)); R.y = exp2_fast(fmaf(-2.f * WC, d1, WC));
        Q.x = exp2_fast(fmaf( 2.f * WC, d0, WC)); Q.y = exp2_fast(fmaf( 2.f * WC, d1, WC));
        const f32x2 E = { E1, E1 };
        char* tb = (char*)&sm.s.tiles[bb][team][0][0][0];
        #pragma unroll
        for (int j = 0; j < 8; ++j) {                   // up: row = c..c+7
            const int row = cI + j;
            *(unsigned*)(tb + row * ROWB + (dimbase ^ ((row & 7) << 4))) =
                pk_bf16(A.x, A.y);
            A = pk_mul(A, R);
            R = pk_mul(R, E);
        }
        A.x = w0; A.y = w1;
        #pragma unroll
        for (int j = 1; j <= 8; ++j) {                  // down: row = c-1..c-8
            const int row = cI - j;
            A = pk_mul(A, Q);
            Q = pk_mul(Q, E);
            *(unsigned*)(tb + row * ROWB + (dimbase ^ ((row & 7) << 4))) =
                pk_bf16(A.x, A.y);
        }
    };

    // MFMA for iteration it from tiles[it&1]
    auto domfma = [&](int it) {
        const int g = (int)blockIdx.x * NTEAM + team + it * (NBLK * NTEAM);
        if (g >= nchunks) return;
        const int bb = it & 1;
        const char* tb = (const char*)&sm.s.tiles[bb][team][0][0][0];
        const int ra = rowblk + l31, ca = colblk + l31;
        const int sa = (ra & 7) << 4, sb = (ca & 7) << 4; // (r+32)&7 == r&7
        #pragma unroll
        for (int s4 = 0; s4 < 2; ++s4) {
            const int kb2 = s4 * 32 + half * 16;          // k-bytes within 64B half
            const short8 a0 = *(const short8*)(tb + ra * ROWB        + ( kb2       ^ sa));
            const short8 a1 = *(const short8*)(tb + (ra + 32) * ROWB + ( kb2       ^ sa));
            const short8 b0 = *(const short8*)(tb + ca * ROWB        + ((kb2 + 64) ^ sb));
            const short8 b1 = *(const short8*)(tb + (ca + 32) * ROWB + ((kb2 + 64) ^ sb));
            acc[0][0] = __builtin_amdgcn_mfma_f32_32x32x16_bf16(a0, b0, acc[0][0], 0, 0, 0);
            acc[0][1] = __builtin_amdgcn_mfma_f32_32x32x16_bf16(a0, b1, acc[0][1], 0, 0, 0);
            acc[1][0] = __builtin_amdgcn_mfma_f32_32x32x16_bf16(a1, b0, acc[1][0], 0, 0, 0);
            acc[1][1] = __builtin_amdgcn_mfma_f32_32x32x16_bf16(a1, b1, acc[1][1], 0, 0, 0);
        }
    };

    // software pipeline: one barrier per iteration; gen(it+1) and stage(it+2)
    // overlap domfma(it) on disjoint buffers.
    stage(0);
    __syncthreads();
    stage(1);
    gen(0);
    __syncthreads();
    for (int it = 0; it < niter; ++it) {
        stage(it + 2);
        domfma(it);
        gen(it + 1);
        __syncthreads();
    }
    // loop ends with a barrier: safe to alias tiles with hist now.

    // merge teams into LDS hist: 4 barrier-ordered passes of plain ds ops.
    // C/D layout (verified R6): row=(r&3)+8*(r>>2)+4*half, col=l31 per tile.
    for (int tm = 0; tm < NTEAM; ++tm) {
        if (team == tm) {
            #pragma unroll
            for (int rb = 0; rb < 2; ++rb)
                #pragma unroll
                for (int tj = 0; tj < 2; ++tj)
                    #pragma unroll
                    for (int r = 0; r < 16; ++r) {
                        const int row = rowblk + rb * 32 + (r & 3) + 8 * (r >> 2) + 4 * half;
                        const int col = colblk + tj * 32 + l31;
                        const int a = row * NBINS + col;
                        const float v = acc[rb][tj][r];
                        if (tm == 0) sm.hist[a] = v;
                        else         sm.hist[a] += v;
                    }
        }
        __syncthreads();
    }

    if (part) {
        // stream the block partial out (64 KB plain coalesced float4 stores)
        // and fold the block sum in the same pass (free ALU under stores);
        // block sum exits via ONE plain store (no atomic, no memset needed).
        float4* dst = (float4*)(part + (size_t)blockIdx.x * NB2);
        const float4* src = (const float4*)sm.hist;
        float s = 0.f;
        for (int i = tid; i < NB2 / 4; i += TPB) {
            const float4 v = src[i];
            dst[i] = v;
            s += v.x + v.y + v.z + v.w;
        }
        #pragma unroll
        for (int off = 32; off > 0; off >>= 1) s += __shfl_down(s, off, 64);
        if (lane == 0) wred[tid >> 6] = s;
        __syncthreads();
        if (tid == 0) {
            float t = 0.f;
            #pragma unroll
            for (int i = 0; i < TPB / 64; ++i) t += wred[i];
            bsum[blockIdx.x] = t;
        }
    } else {
        // fallback: device-atomic merge into out (zeroed host-side)
        for (int i = tid; i < NB2; i += TPB)
            unsafeAtomicAdd(&out[i], sm.hist[i]);
    }
}

// Kernel 2 (partials mode): 256 blocks; block b reduces output elements
// [64b, 64b+64) across the 256 partials (coalesced 256B runs, LLC-resident)
// and normalizes with the global sum folded from bsum[256] (1 KB, local
// reduce — no atomics, no spin; visibility via the dispatch boundary).
__global__ __launch_bounds__(256) void kde_reduce_kernel(
    float* __restrict__ out,
    const float* __restrict__ part,
    const float* __restrict__ bsum,
    const float* __restrict__ ex,
    const float* __restrict__ ey)
{
    __shared__ float smr[4][64];
    __shared__ float sred[4];
    const int tid = (int)threadIdx.x, b = (int)blockIdx.x;
    const int g = tid >> 6, l = tid & 63;

    // global sum from the 256 per-block sums
    float s = bsum[tid];
    #pragma unroll
    for (int off = 32; off > 0; off >>= 1) s += __shfl_down(s, off, 64);
    if (l == 0) sred[g] = s;

    float v = 0.f;
    const float* base = part + b * 64 + l;
    #pragma unroll 4
    for (int p = g; p < NBLK; p += 4)
        v += base[(size_t)p * NB2];
    smr[g][l] = v;
    __syncthreads();

    if (g == 0) {
        const float tot = smr[0][l] + smr[1][l] + smr[2][l] + smr[3][l];
        const float S = sred[0] + sred[1] + sred[2] + sred[3];
        const float inv = (1.0f / (ex[1] - ex[0])) * (1.0f / (ey[1] - ey[0])) / S;
        out[b * 64 + l] = tot * inv;
    }
}

// Kernel 2 (fallback mode): single block; total-reduce, normalize in place.
__global__ __launch_bounds__(1024) void kde_final_kernel(
    float* __restrict__ out,
    const float* __restrict__ ex,
    const float* __restrict__ ey)
{
    __shared__ float red[1024 / 64];
    __shared__ float sinv;
    const int tid = (int)threadIdx.x;

    float4 v[4];
    float s = 0.f;
    #pragma unroll
    for (int i = 0; i < 4; ++i) {
        v[i] = ((const float4*)out)[tid + i * 1024];
        s += v[i].x + v[i].y + v[i].z + v[i].w;
    }
    #pragma unroll
    for (int off = 32; off > 0; off >>= 1) s += __shfl_down(s, off, 64);
    if ((tid & 63) == 0) red[tid >> 6] = s;
    __syncthreads();
    if (tid == 0) {
        float t = 0.f;
        #pragma unroll
        for (int i = 0; i < 1024 / 64; ++i) t += red[i];
        sinv = 1.0f / (t * (ex[1] - ex[0]) * (ey[1] - ey[0]));
    }
    __syncthreads();
    const float inv = sinv;
    #pragma unroll
    for (int i = 0; i < 4; ++i) {
        float4 o = v[i];
        o.x *= inv; o.y *= inv; o.z *= inv; o.w *= inv;
        ((float4*)out)[tid + i * 1024] = o;
    }
}

extern "C" void kernel_launch(void* const* d_in, const int* in_sizes, int n_in,
                              void* d_out, int out_size, void* d_ws, size_t ws_size,
                              hipStream_t stream)
{
    const float* x  = (const float*)d_in[0];
    const float* ex = (const float*)d_in[1];
    const float* ey = (const float*)d_in[2];
    float* out = (float*)d_out;
    const int n = in_sizes[0] / 6;
    const int nchunks = (n + KC - 1) / KC;

    const size_t needPart = (size_t)NBLK * NB2 * sizeof(float)
                          + (size_t)NBLK * sizeof(float);
    if (ws_size >= needPart) {
        float* part = (float*)d_ws;
        float* bsum = part + (size_t)NBLK * NB2;
        kde_mfma_kernel<<<NBLK, TPB, 0, stream>>>(x, ex, ey, out, part, bsum,
                                                  n, nchunks);
        kde_reduce_kernel<<<NBLK, 256, 0, stream>>>(out, part, bsum, ex, ey);
    } else {
        hipMemsetAsync(d_out, 0, NB2 * sizeof(float), stream);
        kde_mfma_kernel<<<NBLK, TPB, 0, stream>>>(x, ex, ey, out,
                                                  nullptr, nullptr, n, nchunks);
        kde_final_kernel<<<1, 1024, 0, stream>>>(out, ex, ey);
    }
}